// Round 7
// baseline (171.424 us; speedup 1.0000x reference)
//
#include <hip/hip_runtime.h>
#include <stdint.h>

// Problem constants (B=16, A=3, H=W=76, ATTR=5+80=85)
// Input:  fp32, shape (16, 255, 76, 76)   = 23,566,080 floats (94.3 MB)
// Output: fp32, shape (16, 3, 76, 76, 85) = 23,566,080 floats (94.3 MB)
#define NB       16
#define NA       3
#define HH_      76
#define WW_      76
#define S_TOT    (HH_ * WW_)          // 5776
#define ATTR     85
#define TILE_S   76                   // one image row per tile
#define NTILES   (NB * NA * HH_)      // 3648 tiles total
#define NBLK     512                  // 2 blocks/CU exactly
#define NTHREADS 512
#define ROWP     96                   // padded LDS row stride (words), %4==0
#define BUFW     8192                 // words per LDS buffer = 32 instr * 256
#define NSTGW    4                    // global_load_lds instrs per wave per tile
#define TW4      1615                 // output float4 granules per tile (76*85/4)
#define LOG2E    1.44269504088896340f

typedef __attribute__((ext_vector_type(4))) float float4v;

// R6 theory: six kernels (R0-R5) pinned at 59-63us across occupancy 44->62%,
// conflicts 1.4M->111K, NT vs cached stores, reg- vs DMA-staging. Common
// structure: per block, read-phase -> full-drain barrier -> write-phase.
// Identical blocks stay lockstep -> the CHIP alternates read-only and
// write-only phases with a latency bubble at each of ~14 generation turns;
// neither HBM direction is fed continuously (63/R + 92/R + bubbles ~ 59us).
// Fix: T3/T4 counted-vmcnt double-buffer. Each of 512 blocks owns ~7 tiles;
// per iteration: issue NEXT tile's staging (4x16B global_load_lds per wave),
// s_waitcnt vmcnt(4) -- next tile's loads stay in flight across the barrier
// (never vmcnt(0) mid-loop) -- raw s_barrier, then compute+store current.
// Reads and writes overlap continuously inside every block; convoy broken.
//
// LDS layout: row k (85 rows) at stride 96 words, rotated by 4*(k>>2) words
// (rotation %4==0 keeps every 16B staging load aligned and within the 76-word
// segment: t0 = p-96k = 0 mod 4 always, so loads never straddle). Phase-2
// read lane stride = 4*96+4 = 388 = 4 mod 32 -> 8 banks, ~2.6-way ~ free.
__global__ __launch_bounds__(NTHREADS, 4)
void yolo_layer_kernel(const float* __restrict__ in,
                       float* __restrict__ out) {
    __shared__ __attribute__((aligned(16))) float lds[2 * BUFW]; // 65,536 B -> 2 blocks/CU

    const int tid  = threadIdx.x;
    const int lane = tid & 63;
    const int wv   = tid >> 6;
    const int b    = blockIdx.x;

    // ---- staging: one tile (lin) -> LDS buffer at word offset bufw ----
    auto STAGE = [&](int bufw, int lin) {
        int tBA = lin / 76;
        int ttr = lin - 76 * tBA;
        const float* binb = in + (size_t)tBA * (ATTR * S_TOT) + ttr * WW_;
        #pragma unroll
        for (int ii = 0; ii < NSTGW; ++ii) {
            int j  = (wv << 2) + ii;          // 0..31, wave-uniform
            int p  = (j << 8) + (lane << 2);  // dest word for this lane
            int k  = p / 96;                  // padded row (<=85)
            int t0 = p - 96 * k;              // 0..92, always %4==0
            int kc = (k > 84) ? 84 : k;
            int rot = (kc >> 2) << 2;         // rotation, %4==0
            int tr = t0 - rot;
            tr += (tr < 0) ? 96 : 0;          // (t0 - rot) mod 96, %4==0
            int ts = (tr <= 72) ? tr : 72;    // pad lane -> safe dup (same segment)
            if (k > 84) ts = 72;              // rows 85+ are never-read pad
            const float* g = binb + (size_t)kc * S_TOT + ts;
            __builtin_amdgcn_global_load_lds(
                (const __attribute__((address_space(1))) void*)g,
                (__attribute__((address_space(3))) void*)&lds[bufw + (j << 8)],
                16, 0, 0);                    // wave-uniform dest + lane*16
        }
    };

    // ---- compute + store: LDS buffer -> out tile lin ----
    auto COMPUTE = [&](int bufw, int lin) {
        int tBA = lin / 76;
        int ttr = lin - 76 * tBA;
        int ta  = tBA - 3 * (tBA / 3);
        // faithful to reference's off-by-one anchor_h: W=[10,13,16], H=[13,16,30]
        float aw = (ta == 0) ? 10.0f : (ta == 1) ? 13.0f : 16.0f;
        float ah = (ta == 0) ? 13.0f : (ta == 1) ? 16.0f : 30.0f;
        float cw = aw * (1.0f / 608.0f);
        float ch = ah * (1.0f / 608.0f);
        float trf = (float)ttr;
        const float* L = &lds[bufw];
        float4v* outv = (float4v*)out + (size_t)lin * TW4;
        #pragma unroll
        for (int i = 0; i < 4; ++i) {
            int u = tid + i * NTHREADS;
            if (u >= TW4) break;
            int idx0 = u << 2;                // tile elem = s*85 + k
            int s  = idx0 / 85;               // one magic-div per granule
            int k0 = idx0 - 85 * s;
            float r[4];
            #pragma unroll
            for (int e = 0; e < 4; ++e) {
                int k    = k0 + e;
                int w    = (k >= 85) ? 1 : 0; // granule wraps into next s
                int keff = k - 85 * w;
                int seff = s + w;
                int rot  = (keff >> 2) << 2;
                int t    = seff + rot;
                t -= (t >= 96) ? 96 : 0;
                float x  = L[keff * 96 + t];
                float E  = __builtin_amdgcn_exp2f(x * (-LOG2E)); // e^-x
                float sg = __builtin_amdgcn_rcpf(1.0f + E);      // sigmoid
                float rv;
                if (keff >= 4)      rv = sg;                     // conf+classes (95%)
                else if (keff == 0) rv = ((float)seff + sg) * (1.0f / 76.0f); // bx, wx=seff
                else if (keff == 1) rv = (trf + sg) * (1.0f / 76.0f);         // by, hy=row
                else rv = __builtin_amdgcn_rcpf(E) *             // e^x = 1/E
                          ((keff == 2) ? cw : ch);               // bw / bh
                r[e] = rv;
            }
            float4v w4 = { r[0], r[1], r[2], r[3] };
            outv[u] = w4;                     // consecutive lanes -> 16B coalesced
        }
    };

    // ---- pipelined main loop over this block's tiles (b, b+512, ...) ----
    const int n = (b < NTILES - 7 * NBLK) ? 8 : 7;   // 3648 = 512*7 + 64
    STAGE(0, b);                                      // prologue: tile 0 -> buf0
    for (int i = 0; ; ) {
        int lin = b + i * NBLK;
        if (i + 1 < n) {
            STAGE(((i + 1) & 1) * BUFW, lin + NBLK);  // next tile in flight
            // wait until only the 4 next-tile loads remain outstanding:
            // current tile fully landed, old stores drained (vmcnt in-order).
            asm volatile("s_waitcnt vmcnt(4)" ::: "memory");
        } else {
            asm volatile("s_waitcnt vmcnt(0)" ::: "memory");
        }
        __builtin_amdgcn_sched_barrier(0);
        __builtin_amdgcn_s_barrier();
        __builtin_amdgcn_sched_barrier(0);
        COMPUTE((i & 1) * BUFW, lin);
        if (++i >= n) break;
        __builtin_amdgcn_sched_barrier(0);
        __builtin_amdgcn_s_barrier();      // all ds_reads of this buf done before
    }                                      // next iteration stages into it
}

extern "C" void kernel_launch(void* const* d_in, const int* in_sizes, int n_in,
                              void* d_out, int out_size, void* d_ws, size_t ws_size,
                              hipStream_t stream) {
    const float* in = (const float*)d_in[0];   // fp32 input
    float* out = (float*)d_out;                // fp32 output

    dim3 grid(NBLK);        // 512 blocks = 2 per CU, each owns ~7 tiles
    dim3 block(NTHREADS);
    yolo_layer_kernel<<<grid, block, 0, stream>>>(in, out);
}

// Round 8
// 169.771 us; speedup vs baseline: 1.0097x; 1.0097x over previous
//
#include <hip/hip_runtime.h>
#include <stdint.h>

// Problem constants (B=16, A=3, H=W=76, ATTR=5+80=85)
// Input:  fp32, shape (16, 255, 76, 76)   = 94.3 MB ; Output same size.
#define NB       16
#define NA       3
#define S_TOT    5776                 // 76*76
#define ATTR     85
#define TILE_S   76                   // one image row per tile
#define NTILES   3648                 // 48 BA * 76 rows
#define NBLK     768                  // persistent blocks = 3 per CU
#define NTHREADS 512
#define TILEW    (TILE_S * ATTR)      // 6460 words per tile
#define UNITS1   (22 * TILE_S)        // 1672 load/scatter units (s x k-quad)
#define UNITS2   (TILEW / 4)          // 1615 output float4 granules
#define LOG2E    1.44269504088896340f

typedef __attribute__((ext_vector_type(4))) float float4v;

__device__ __forceinline__ float fast_sigmoid(float x) {
    float e = __builtin_amdgcn_exp2f(x * (-LOG2E));
    return __builtin_amdgcn_rcpf(1.0f + e);
}

// R7: the convoy theory, implemented correctly this time.
// R6's failure was implementation: vmcnt(4) also counted the (younger) stores,
// draining the store stream every iteration; and the swizzle gave lane stride
// 388 = 4 mod 32 -> 8-way conflicts; and 16 waves/CU. Fixes here:
//  - REGISTER staging + NO manual vmcnt: the compiler inserts minimal waits
//    before each v[] use (correctly counting the younger stores as
//    outstanding-allowed). Stores are never waited on; endpgm drains them.
//  - sched_barrier(0) walls stop the compiler sinking the hoisted loads
//    (R2/R3's VGPR=20 disease).
//  - raw s_barrier with lgkmcnt(0)-only drain (never __syncthreads: it emits
//    s_waitcnt vmcnt(0) and would drain loads AND stores at every barrier).
//  - R3's proven LDS mapping: scatter-write lane stride 85 words (odd -> all
//    32 banks, 2-way = free), phase-2 = contiguous b128 reads (conflict-free).
//  - 768 persistent blocks = 3/CU, 24 waves/CU; one barrier per iteration;
//    reads and writes in flight continuously in every wave.
__global__ __launch_bounds__(NTHREADS, 6)
void yolo_layer_kernel(const float* __restrict__ in,
                       float* __restrict__ out) {
    __shared__ __attribute__((aligned(16))) float lds[2][TILEW]; // 51,680 B -> 3 blk/CU

    const int tid = threadIdx.x;
    const int b   = blockIdx.x;
    // 3648 = 768*4 + 576 : blocks 0..575 own 5 tiles, 576..767 own 4.
    const int n   = (b < NTILES - 4 * NBLK) ? 5 : 4;

    float v[4][4];   // raw staged tile (16 floats), lives across compute

    // ---- issue 16 raw b32 loads for tile lin (cross-lane contiguous in s) ----
    auto LOADR = [&](int lin) {
        int tBA = lin / TILE_S;
        int row = lin - tBA * TILE_S;
        const float* inb = in + (size_t)tBA * (ATTR * S_TOT) + row * TILE_S;
        #pragma unroll
        for (int i = 0; i < 4; ++i) {
            int u  = tid + i * NTHREADS;
            int uc = (u < UNITS1) ? u : 0;     // tail lanes: safe dup loads
            int g  = uc / TILE_S;              // k-quad 0..21
            int s  = uc - g * TILE_S;
            const float* p = inb + s;
            #pragma unroll
            for (int q = 0; q < 4; ++q) {
                int k = 4 * g + q;
                if (k > 84) k = 84;            // g==21 tail: dup of row 84
                v[i][q] = p[(size_t)k * S_TOT];
            }
        }
    };

    // ---- math on v + scatter into lds[sel] (lane stride 85 = odd -> free) ----
    auto MATHSCATTER = [&](int lin, int sel) {
        int tBA = lin / TILE_S;
        int row = lin - tBA * TILE_S;
        int ta  = tBA - 3 * (tBA / 3);
        // faithful to reference's off-by-one anchor_h: W=[10,13,16], H=[13,16,30]
        float aw = (ta == 0) ? 10.0f : (ta == 1) ? 13.0f : 16.0f;
        float ah = (ta == 0) ? 13.0f : (ta == 1) ? 16.0f : 30.0f;
        float cw = aw * (1.0f / 608.0f);
        float ch = ah * (1.0f / 608.0f);
        float rowf = (float)row;
        #pragma unroll
        for (int i = 0; i < 4; ++i) {
            int u = tid + i * NTHREADS;
            if (u >= UNITS1) break;
            int g = u / TILE_S;
            int s = u - g * TILE_S;
            float r[4];
            if (g != 0) {
                #pragma unroll
                for (int q = 0; q < 4; ++q) r[q] = fast_sigmoid(v[i][q]);
            } else {
                // k=0..3 : bx,by,bw,bh ; wx = s, hy = row
                r[0] = ((float)s + fast_sigmoid(v[i][0])) * (1.0f / 76.0f);
                r[1] = (rowf + fast_sigmoid(v[i][1])) * (1.0f / 76.0f);
                r[2] = __builtin_amdgcn_exp2f(v[i][2] * LOG2E) * cw;
                r[3] = __builtin_amdgcn_exp2f(v[i][3] * LOG2E) * ch;
            }
            float* lp = &lds[sel][s * ATTR + 4 * g];
            #pragma unroll
            for (int q = 0; q < 4; ++q)
                if (4 * g + q < ATTR) lp[q] = r[q];   // guard g==21 dups
        }
    };

    // ---- contiguous b128 LDS reads -> coalesced global stores (never waited) --
    auto COMPUTESTORE = [&](int lin, int sel) {
        const float4v* ldsv = (const float4v*)&lds[sel][0];
        float4v* outv = (float4v*)out + (size_t)lin * UNITS2;
        #pragma unroll
        for (int i = 0; i < 4; ++i) {
            int u = tid + i * NTHREADS;
            if (u >= UNITS2) break;
            float4v w = ldsv[u];
            outv[u] = w;
        }
    };

    // ---- prologue: tile 0 -> buf0 ----
    LOADR(b);
    __builtin_amdgcn_sched_barrier(0);
    MATHSCATTER(b, 0);                       // compiler-inserted vmcnt before v use
    asm volatile("s_waitcnt lgkmcnt(0)" ::: "memory");
    __builtin_amdgcn_sched_barrier(0);
    __builtin_amdgcn_s_barrier();
    __builtin_amdgcn_sched_barrier(0);

    // ---- steady state: one barrier per iteration, stores free-running ----
    for (int t = 0; t < n; ++t) {
        int lin = b + t * NBLK;
        if (t + 1 < n) {
            LOADR(lin + NBLK);               // tile t+1 in flight across compute
            __builtin_amdgcn_sched_barrier(0);
        }
        COMPUTESTORE(lin, t & 1);            // reads buf t&1; writes global
        if (t + 1 < n) {
            __builtin_amdgcn_sched_barrier(0);
            MATHSCATTER(lin + NBLK, (t + 1) & 1);  // other buffer: no pre-barrier
            asm volatile("s_waitcnt lgkmcnt(0)" ::: "memory");
            __builtin_amdgcn_sched_barrier(0);
            __builtin_amdgcn_s_barrier();    // writes visible before next compute
            __builtin_amdgcn_sched_barrier(0);
        }
    }
}

extern "C" void kernel_launch(void* const* d_in, const int* in_sizes, int n_in,
                              void* d_out, int out_size, void* d_ws, size_t ws_size,
                              hipStream_t stream) {
    const float* in = (const float*)d_in[0];   // fp32 input
    float* out = (float*)d_out;                // fp32 output

    dim3 grid(NBLK);        // 768 persistent blocks = 3/CU, 4-5 tiles each
    dim3 block(NTHREADS);
    yolo_layer_kernel<<<grid, block, 0, stream>>>(in, out);
}